// Round 9
// baseline (167.575 us; speedup 1.0000x reference)
//
#include <hip/hip_runtime.h>
#include <stdint.h>

#define NB 32
#define NN 25200
#define NN4 6300          // NN/4, exact
#define TOPK 1024
#define NF 16
#define CONF 0.25f
#define IOU_T 0.45f
#define NBIN 4096
#define CAP 2048
#define KEY_BASE 0xBE800001u  // lowest possible valid key (score just above 0.25)

typedef unsigned int u32x4 __attribute__((ext_vector_type(4)));

// monotone-ascending uint32 map of the reference's s = valid ? obj*cls : -1.0
// Valid entries (obj>CONF && score>CONF) map to keys >= KEY_BASE; all invalid
// entries (s=-1.0 -> 0x407FFFFF) land strictly below KEY_BASE.
__device__ __forceinline__ uint32_t score_key(float obj, float cls) {
  float score = __fmul_rn(cls, obj);
  bool valid = (obj > CONF) && (score > CONF);
  float s = valid ? score : -1.0f;
  uint32_t u = __float_as_uint(s);
  return (u & 0x80000000u) ? ~u : (u | 0x80000000u);
}

__device__ __forceinline__ uint64_t shfl_xor_u64(uint64_t v, int m) {
  uint32_t lo = __shfl_xor((uint32_t)v, m, 64);
  uint32_t hi = __shfl_xor((uint32_t)(v >> 32), m, 64);
  return ((uint64_t)hi << 32) | lo;
}

// Full-grid key compute: the 51.6 MB strided pred read spread over all 256 CUs
// (R8 lesson: folding this into the 32-block select kernel is a 5x loss).
// Also zeroes the per-image slab counters for the fused mask+scan kernel.
__global__ void k_keys(const float* __restrict__ pred, uint32_t* __restrict__ keys,
                       uint32_t* __restrict__ cnt) {
  if (blockIdx.x == 0 && threadIdx.x < NB) cnt[threadIdx.x] = 0u;
  int g = blockIdx.x * blockDim.x + threadIdx.x;
  if (g >= NB * NN) return;
  const float* row = pred + (size_t)g * NF;
  keys[g] = score_key(row[4], row[15]);
}

// One block per image. Keys read ONCE into registers (<=7 uint4/thread);
// uniform 4096-bin histogram over the valid-key range -> suffix-scan for the
// rank-1024 crossing bin -> compact bins >= b* (~1026 els, CAP=2048
// zero-padded) -> register bitonic 2048 descending on (key32<<32 | ~n).
// Exact jax.lax.top_k order. Epilogue materializes boxes/areas/validity so
// downstream kernels never gather pred again except for the final output row.
__global__ __launch_bounds__(1024) void k_select(const float* __restrict__ pred,
                                                 const uint32_t* __restrict__ keys,
                                                 int* __restrict__ sel,
                                                 float4* __restrict__ boxv,
                                                 float* __restrict__ arv,
                                                 uint32_t* __restrict__ vb) {
  int b = blockIdx.x;
  int tid = threadIdx.x;
  int lane = tid & 63, wid = tid >> 6;
  const uint4* kb4 = (const uint4*)(keys + (size_t)b * NN);
  __shared__ uint32_t hist[NBIN];
  __shared__ uint64_t ent[CAP];
  __shared__ uint32_t wsum[16];
  __shared__ uint32_t sh_bin;
  __shared__ uint32_t sh_cnt;
  #pragma unroll
  for (int k = 0; k < 4; ++k) hist[tid + 1024 * k] = 0;
  ent[tid] = 0; ent[tid + 1024] = 0;
  if (tid == 0) { sh_cnt = 0; sh_bin = 0; }
  __syncthreads();

  // phase 1: load keys into registers (single global pass) + histogram
  uint4 kreg[7];
  #pragma unroll
  for (int k = 0; k < 7; ++k) {
    int i = tid + k * 1024;
    if (i < NN4) {
      kreg[k] = kb4[i];
      uint32_t kv[4] = {kreg[k].x, kreg[k].y, kreg[k].z, kreg[k].w};
      #pragma unroll
      for (int c = 0; c < 4; ++c) {
        uint32_t key = kv[c];
        if (key >= KEY_BASE) {
          uint32_t bin = (key - KEY_BASE) >> 12;
          if (bin > NBIN - 1) bin = NBIN - 1;
          atomicAdd(&hist[bin], 1u);
        }
      }
    }
  }
  __syncthreads();

  // phase 2: descending-bin cumulative via shfl scan; find crossing bin
  uint32_t h[4]; uint32_t s = 0;
  #pragma unroll
  for (int k = 0; k < 4; ++k) { h[k] = hist[NBIN - 1 - (4 * tid + k)]; s += h[k]; }
  uint32_t my = s;
  #pragma unroll
  for (int d = 1; d < 64; d <<= 1) {
    uint32_t v = __shfl_up(s, d, 64);
    if (lane >= d) s += v;
  }
  if (lane == 63) wsum[wid] = s;
  __syncthreads();
  uint32_t base = 0;
  for (int w = 0; w < wid; ++w) base += wsum[w];
  uint32_t cum = base + s - my;  // exclusive prefix (descending bins)
  #pragma unroll
  for (int k = 0; k < 4; ++k) {
    if (cum < TOPK && cum + h[k] >= TOPK) sh_bin = (uint32_t)(NBIN - 1 - (4 * tid + k));
    cum += h[k];
  }
  __syncthreads();
  uint32_t thr = KEY_BASE + (sh_bin << 12);

  // phase 3: compact from registers (no second global pass)
  #pragma unroll
  for (int k = 0; k < 7; ++k) {
    int i = tid + k * 1024;
    if (i < NN4) {
      uint32_t kv[4] = {kreg[k].x, kreg[k].y, kreg[k].z, kreg[k].w};
      #pragma unroll
      for (int c = 0; c < 4; ++c) {
        uint32_t key = kv[c];
        if (key >= thr) {
          uint32_t p = atomicAdd(&sh_cnt, 1u);
          if (p < CAP) ent[p] = ((uint64_t)key << 32) | (uint32_t)(~(uint32_t)(4 * i + c));
        }
      }
    }
  }
  __syncthreads();

  // phase 4: register bitonic, 2048 descending, 2 elems/thread
  uint64_t v0 = ent[tid], v1 = ent[tid + 1024];
  for (unsigned kk = 2; kk <= CAP; kk <<= 1) {
    for (unsigned j = kk >> 1; j > 0; j >>= 1) {
      if (j == 1024) {
        uint64_t mx = v0 > v1 ? v0 : v1;
        uint64_t mn = v0 > v1 ? v1 : v0;
        v0 = mx; v1 = mn;  // desc=true for kk=2048
      } else if (j >= 64) {
        __syncthreads();
        ent[tid] = v0; ent[tid + 1024] = v1;
        __syncthreads();
        uint64_t p0 = ent[tid ^ j], p1 = ent[(tid ^ j) + 1024];
        bool low = ((tid & j) == 0);
        bool d0 = ((tid & kk) == 0);
        bool d1 = (((tid + 1024) & kk) == 0);
        v0 = (low != d0) ? (v0 < p0 ? v0 : p0) : (v0 > p0 ? v0 : p0);
        v1 = (low != d1) ? (v1 < p1 ? v1 : p1) : (v1 > p1 ? v1 : p1);
      } else {
        uint64_t p0 = shfl_xor_u64(v0, (int)j);
        uint64_t p1 = shfl_xor_u64(v1, (int)j);
        bool low = ((tid & j) == 0);
        bool d0 = ((tid & kk) == 0);
        bool d1 = (((tid + 1024) & kk) == 0);
        v0 = (low != d0) ? (v0 < p0 ? v0 : p0) : (v0 > p0 ? v0 : p0);
        v1 = (low != d1) ? (v1 < p1 ? v1 : p1) : (v1 > p1 ? v1 : p1);
      }
    }
  }
  uint32_t key = (uint32_t)(v0 >> 32);
  uint32_t n = ~(uint32_t)(v0 & 0xFFFFFFFFu);
  if (n >= NN) n = 0;  // zero-pad path (fewer than 1024 above threshold)
  sel[(size_t)b * TOPK + tid] = (int)n;

  // validity ballot (rank order == tid order; word w covers ranks 32w..32w+31)
  bool valid = key >= KEY_BASE;
  uint64_t bal = __ballot(valid);
  if (lane == 0) {
    vb[(size_t)b * 32 + 2 * wid] = (uint32_t)bal;
    vb[(size_t)b * 32 + 2 * wid + 1] = (uint32_t)(bal >> 32);
  }

  // boxes + areas: the ONE scattered pred gather per image (identical float
  // ops to the old k_mask conversion, so downstream bits are unchanged)
  {
    const float4* row = (const float4*)(pred + ((size_t)b * NN + n) * NF);
    float4 r0 = row[0];
    float hw = __fmul_rn(r0.z, 0.5f), hh = __fmul_rn(r0.w, 0.5f);
    float x1 = __fsub_rn(r0.x, hw), y1 = __fsub_rn(r0.y, hh);
    float x2 = __fadd_rn(r0.x, hw), y2 = __fadd_rn(r0.y, hh);
    boxv[(size_t)b * TOPK + tid] = make_float4(x1, y1, x2, y2);
    arv[(size_t)b * TOPK + tid] = __fmul_rn(__fsub_rn(x2, x1), __fsub_rn(y2, y1));
  }
}

// One resolve round of the word-serial greedy scan (R8 branchless/readlane
// form — neutral vs __shfl but keeps lgkm out of the broadcast path).
#define RESOLVE(CUR, W)                                                    \
  {                                                                        \
    uint32_t rw = kw;                                                      \
    _Pragma("unroll")                                                      \
    for (int t = 0; t < 32; ++t) {                                         \
      uint32_t m = (uint32_t)(((int32_t)(rw << (31 - t))) >> 31);          \
      rw &= ~(m & CUR[t]);                                                 \
    }                                                                      \
    uint32_t rf = (uint32_t)__builtin_amdgcn_readlane(rw, (W));            \
    uint32_t a0 = 0, a1 = 0, a2 = 0, a3 = 0;                               \
    _Pragma("unroll")                                                      \
    for (int t = 0; t < 32; t += 4) {                                      \
      a0 |= (0u - ((rf >> t) & 1u)) & CUR[t];                              \
      a1 |= (0u - ((rf >> (t + 1)) & 1u)) & CUR[t + 1];                    \
      a2 |= (0u - ((rf >> (t + 2)) & 1u)) & CUR[t + 2];                    \
      a3 |= (0u - ((rf >> (t + 3)) & 1u)) & CUR[t + 3];                    \
    }                                                                      \
    uint32_t acc = (a0 | a1) | (a2 | a3);                                  \
    uint32_t nkw = kw & ~acc;                                              \
    nkw = (l > (W)) ? nkw : kw;                                            \
    kw = (l == (W)) ? rf : nkw;                                            \
  }

// R9: fused mask + scan + output; RELEASE WRITEBACK MADE EMPTY.
// R6-R8 evidence: tail ~50us is spin-dominated (~35us) even though the scan
// block's own slab-0 is the heaviest — the waiters wait on the RELEASES, not
// the mask work. Each of 256 blocks' agent-scope RELEASE fetch_add emits a
// buffer_wbl2 (dirty-L2 writeback to the MALL coherence point); 32 per XCD
// serialize at the shared L2 (~2-3k cyc each) -> last release lands ~30us
// after mask end. Fix: store the mask slab with NON-TEMPORAL stores
// (global_store_dwordx4 nt -> write through/past L2 toward MALL), so each
// release's wbl2 finds nothing dirty and completes fast. Consumer side
// unchanged (its caches never held slabs 1-7; single acquire kept for the
// ordering edge). Everything else byte-identical to R8.
__global__ __launch_bounds__(1024, 4) void k_maskscan(const float* __restrict__ pred,
                                                      const int* __restrict__ sel,
                                                      const float4* __restrict__ boxv,
                                                      const float* __restrict__ arv,
                                                      const uint32_t* __restrict__ vb,
                                                      uint32_t* __restrict__ mask,
                                                      uint32_t* __restrict__ cnt,
                                                      float* __restrict__ det,
                                                      float* __restrict__ keep_out) {
  int b = blockIdx.x;
  int sblk = blockIdx.y;
  int tid = threadIdx.x;
  int rg = tid & 31;
  int cc = tid >> 5;
  __shared__ uint32_t smask[32 * 1024];   // 128 KiB; first 20 KB doubles as box arrays in phase A
  float* bx1 = (float*)smask;
  float* by1 = bx1 + TOPK;
  float* bx2 = by1 + TOPK;
  float* by2 = bx2 + TOPK;
  float* bar = by2 + TOPK;

  // ---- phase A: mask slab (identical arithmetic to R6/R7/R8) ----
  {
    float4 bb = boxv[(size_t)b * TOPK + tid];
    bx1[tid] = bb.x; by1[tid] = bb.y; bx2[tid] = bb.z; by2[tid] = bb.w;
    bar[tid] = arv[(size_t)b * TOPK + tid];
  }
  __syncthreads();
  int i0 = sblk * 128 + rg * 4;   // rows i0..i0+3, all in word iw
  int iw = i0 >> 5;
  uint32_t wreg[4] = {0u, 0u, 0u, 0u};
  if (cc >= iw) {
    float rx1[4], ry1[4], rx2[4], ry2[4], rar[4];
    #pragma unroll
    for (int k = 0; k < 4; ++k) {
      rx1[k] = bx1[i0 + k]; ry1[k] = by1[i0 + k];
      rx2[k] = bx2[i0 + k]; ry2[k] = by2[i0 + k]; rar[k] = bar[i0 + k];
    }
    for (int jj = 0; jj < 32; ++jj) {
      int j = cc * 32 + jj;
      float cx1 = bx1[j], cy1 = by1[j], cx2 = bx2[j], cy2 = by2[j], car = bar[j];
      #pragma unroll
      for (int k = 0; k < 4; ++k) {
        float lx = fmaxf(rx1[k], cx1);
        float ly = fmaxf(ry1[k], cy1);
        float rx = fminf(rx2[k], cx2);
        float ry = fminf(ry2[k], cy2);
        float wd = fmaxf(__fsub_rn(rx, lx), 0.0f);
        float ht = fmaxf(__fsub_rn(ry, ly), 0.0f);
        float inter = __fmul_rn(wd, ht);
        float den = __fadd_rn(__fsub_rn(__fadd_rn(rar[k], car), inter), 1e-7f);
        float iou = __fdiv_rn(inter, den);
        wreg[k] |= (iou > IOU_T ? 1u : 0u) << jj;
      }
    }
    if (cc == iw) {
      #pragma unroll
      for (int k = 0; k < 4; ++k)
        wreg[k] &= ~((2u << ((i0 + k) & 31)) - 1u);  // keep only j > i
    }
  }
  // non-temporal slab store: keeps the producer L2 clean so the release's
  // wbl2 has nothing to write back (the R9 fix)
  {
    u32x4 o = {wreg[0], wreg[1], wreg[2], wreg[3]};
    __builtin_nontemporal_store(o, (u32x4*)&mask[((size_t)b * 32 + cc) * TOPK + i0]);
  }

  // publish this slab: barrier drains every thread's vmcnt (nt stores have
  // reached the coherence point), then ONE release-add bumps the counter.
  __syncthreads();
  if (tid == 0)
    __hip_atomic_fetch_add(&cnt[b], 1u, __ATOMIC_RELEASE, __HIP_MEMORY_SCOPE_AGENT);
  if (sblk != 0) return;

  // ---- phase B (sblk==0 only) ----
  // early-issue: scan seed + the OUTPUT gather (latency hides under
  // spin + stage + scan)
  uint32_t kw0 = 0;
  if (tid < 32) kw0 = vb[(size_t)b * 32 + tid];
  int n = sel[(size_t)b * TOPK + tid];
  const float4* rowv = (const float4*)(pred + ((size_t)b * NN + n) * NF);
  float4 r0 = rowv[0], r1 = rowv[1], r2 = rowv[2], r3 = rowv[3];

  if (tid == 0) {
    // RELAXED polls (no cache maintenance); single acquire edge after exit.
    while (__hip_atomic_load(&cnt[b], __ATOMIC_RELAXED, __HIP_MEMORY_SCOPE_AGENT) < 8u)
      __builtin_amdgcn_s_sleep(16);
    (void)__hip_atomic_load(&cnt[b], __ATOMIC_ACQUIRE, __HIP_MEMORY_SCOPE_AGENT);
  }
  __syncthreads();

  // bulk stage: 1024 threads x 8 uint4 = 128 KiB, coalesced; uint4-granular
  // XOR swizzle (col4 ^ (row&7)) applied identically on write and read.
  const uint4* gm4 = (const uint4*)(mask + (size_t)b * (32 * TOPK));
  uint4* sm4 = (uint4*)smask;
  #pragma unroll
  for (int q = 0; q < 8; ++q) {
    int idx4 = tid + q * 1024;          // uint4 index 0..8191
    int row = idx4 >> 8;                // 256 uint4 per row
    int col4 = idx4 & 255;
    sm4[row * 256 + (col4 ^ (row & 7))] = gm4[idx4];
  }
  __syncthreads();

  if (tid < 32) {
    int l = tid;
    const int rbase = l * 256;
    const int sw = l & 7;
    uint32_t kw = kw0;
    uint32_t curA[32], curB[32];
    // preload round 0
    #pragma unroll
    for (int q = 0; q < 8; ++q) *(uint4*)&curA[4 * q] = sm4[rbase + (q ^ sw)];
    #pragma unroll 1
    for (int w = 0; w < 32; w += 2) {
      // even round: consume curA, prefetch w+1 into curB first
      if (w + 1 < 32) {
        #pragma unroll
        for (int q = 0; q < 8; ++q)
          *(uint4*)&curB[4 * q] = sm4[rbase + (w + 1) * 8 + (q ^ sw)];
      }
      RESOLVE(curA, w)
      // odd round: consume curB, prefetch w+2 into curA first
      if (w + 2 < 32) {
        #pragma unroll
        for (int q = 0; q < 8; ++q)
          *(uint4*)&curA[4 * q] = sm4[rbase + (w + 2) * 8 + (q ^ sw)];
      }
      RESOLVE(curB, w + 1)
    }
    smask[l] = kw;   // publish keep word l (that LDS region is fully consumed)
  }
  __syncthreads();

  // output phase: row already in registers (gathered before the spin)
  bool kept = (smask[tid >> 5] >> (tid & 31)) & 1u;
  float m = kept ? 1.0f : 0.0f;
  float score = __fmul_rn(r3.w, r1.x);   // == cls*obj, identical to reference path
  float hw = __fmul_rn(r0.z, 0.5f), hh = __fmul_rn(r0.w, 0.5f);
  float4 o0 = make_float4(__fsub_rn(r0.x, hw) * m, __fsub_rn(r0.y, hh) * m,
                          __fadd_rn(r0.x, hw) * m, __fadd_rn(r0.y, hh) * m);
  float4 o1 = make_float4(score * m, r1.y * m, r1.z * m, r1.w * m);
  float4 o2 = make_float4(r2.x * m, r2.y * m, r2.z * m, r2.w * m);
  float4 o3 = make_float4(r3.x * m, r3.y * m, r3.z * m, 0.0f);
  float4* dst = (float4*)(det + ((size_t)b * TOPK + tid) * NF);
  dst[0] = o0; dst[1] = o1; dst[2] = o2; dst[3] = o3;
  keep_out[(size_t)b * TOPK + tid] = m;
}

extern "C" void kernel_launch(void* const* d_in, const int* in_sizes, int n_in,
                              void* d_out, int out_size, void* d_ws, size_t ws_size,
                              hipStream_t stream) {
  const float* pred = (const float*)d_in[0];
  float* det = (float*)d_out;
  float* keep = det + (size_t)NB * TOPK * NF;

  uint8_t* ws = (uint8_t*)d_ws;
  size_t off = 0;
  uint32_t* keys = (uint32_t*)(ws + off); off += (size_t)NB * NN * 4;
  int* sel = (int*)(ws + off);            off += (size_t)NB * TOPK * 4;
  uint32_t* mask = (uint32_t*)(ws + off); off += (size_t)NB * 32 * TOPK * 4;
  float4* boxv = (float4*)(ws + off);     off += (size_t)NB * TOPK * 16;
  float* arv = (float*)(ws + off);        off += (size_t)NB * TOPK * 4;
  uint32_t* vb = (uint32_t*)(ws + off);   off += (size_t)NB * 32 * 4;
  uint32_t* cnt = (uint32_t*)(ws + off);  off += (size_t)NB * 4;

  k_keys<<<(NB * NN + 255) / 256, 256, 0, stream>>>(pred, keys, cnt);
  k_select<<<NB, 1024, 0, stream>>>(pred, keys, sel, boxv, arv, vb);
  dim3 gm(NB, 8);
  k_maskscan<<<gm, 1024, 0, stream>>>(pred, sel, boxv, arv, vb, mask, cnt, det, keep);
}

// Round 10
// 145.719 us; speedup vs baseline: 1.1500x; 1.1500x over previous
//
#include <hip/hip_runtime.h>
#include <stdint.h>

#define NB 32
#define NN 25200
#define NN4 6300          // NN/4, exact
#define TOPK 1024
#define NF 16
#define CONF 0.25f
#define IOU_T 0.45f
#define NBIN 4096
#define CAP 2048
#define KEY_BASE 0xBE800001u  // lowest possible valid key (score just above 0.25)
#define PITCH 257             // uint4 row pitch in LDS (bank-spread, no swizzle)

// monotone-ascending uint32 map of the reference's s = valid ? obj*cls : -1.0
// Valid entries (obj>CONF && score>CONF) map to keys >= KEY_BASE; all invalid
// entries (s=-1.0 -> 0x407FFFFF) land strictly below KEY_BASE.
__device__ __forceinline__ uint32_t score_key(float obj, float cls) {
  float score = __fmul_rn(cls, obj);
  bool valid = (obj > CONF) && (score > CONF);
  float s = valid ? score : -1.0f;
  uint32_t u = __float_as_uint(s);
  return (u & 0x80000000u) ? ~u : (u | 0x80000000u);
}

__device__ __forceinline__ uint64_t shfl_xor_u64(uint64_t v, int m) {
  uint32_t lo = __shfl_xor((uint32_t)v, m, 64);
  uint32_t hi = __shfl_xor((uint32_t)(v >> 32), m, 64);
  return ((uint64_t)hi << 32) | lo;
}

// Full-grid key compute: the 51.6 MB strided pred read spread over all 256 CUs.
// Also zeroes the per-image slab counters for the fused mask+scan kernel.
__global__ void k_keys(const float* __restrict__ pred, uint32_t* __restrict__ keys,
                       uint32_t* __restrict__ cnt) {
  if (blockIdx.x == 0 && threadIdx.x < NB) cnt[threadIdx.x] = 0u;
  int g = blockIdx.x * blockDim.x + threadIdx.x;
  if (g >= NB * NN) return;
  const float* row = pred + (size_t)g * NF;
  keys[g] = score_key(row[4], row[15]);
}

// One block per image. Keys read ONCE into registers; histogram -> crossing
// bin -> compact -> register bitonic 2048 descending. Exact jax.lax.top_k
// order. Epilogue materializes boxes/areas/validity.
__global__ __launch_bounds__(1024) void k_select(const float* __restrict__ pred,
                                                 const uint32_t* __restrict__ keys,
                                                 int* __restrict__ sel,
                                                 float4* __restrict__ boxv,
                                                 float* __restrict__ arv,
                                                 uint32_t* __restrict__ vb) {
  int b = blockIdx.x;
  int tid = threadIdx.x;
  int lane = tid & 63, wid = tid >> 6;
  const uint4* kb4 = (const uint4*)(keys + (size_t)b * NN);
  __shared__ uint32_t hist[NBIN];
  __shared__ uint64_t ent[CAP];
  __shared__ uint32_t wsum[16];
  __shared__ uint32_t sh_bin;
  __shared__ uint32_t sh_cnt;
  #pragma unroll
  for (int k = 0; k < 4; ++k) hist[tid + 1024 * k] = 0;
  ent[tid] = 0; ent[tid + 1024] = 0;
  if (tid == 0) { sh_cnt = 0; sh_bin = 0; }
  __syncthreads();

  // phase 1: load keys into registers (single global pass) + histogram
  uint4 kreg[7];
  #pragma unroll
  for (int k = 0; k < 7; ++k) {
    int i = tid + k * 1024;
    if (i < NN4) {
      kreg[k] = kb4[i];
      uint32_t kv[4] = {kreg[k].x, kreg[k].y, kreg[k].z, kreg[k].w};
      #pragma unroll
      for (int c = 0; c < 4; ++c) {
        uint32_t key = kv[c];
        if (key >= KEY_BASE) {
          uint32_t bin = (key - KEY_BASE) >> 12;
          if (bin > NBIN - 1) bin = NBIN - 1;
          atomicAdd(&hist[bin], 1u);
        }
      }
    }
  }
  __syncthreads();

  // phase 2: descending-bin cumulative via shfl scan; find crossing bin
  uint32_t h[4]; uint32_t s = 0;
  #pragma unroll
  for (int k = 0; k < 4; ++k) { h[k] = hist[NBIN - 1 - (4 * tid + k)]; s += h[k]; }
  uint32_t my = s;
  #pragma unroll
  for (int d = 1; d < 64; d <<= 1) {
    uint32_t v = __shfl_up(s, d, 64);
    if (lane >= d) s += v;
  }
  if (lane == 63) wsum[wid] = s;
  __syncthreads();
  uint32_t base = 0;
  for (int w = 0; w < wid; ++w) base += wsum[w];
  uint32_t cum = base + s - my;  // exclusive prefix (descending bins)
  #pragma unroll
  for (int k = 0; k < 4; ++k) {
    if (cum < TOPK && cum + h[k] >= TOPK) sh_bin = (uint32_t)(NBIN - 1 - (4 * tid + k));
    cum += h[k];
  }
  __syncthreads();
  uint32_t thr = KEY_BASE + (sh_bin << 12);

  // phase 3: compact from registers (no second global pass)
  #pragma unroll
  for (int k = 0; k < 7; ++k) {
    int i = tid + k * 1024;
    if (i < NN4) {
      uint32_t kv[4] = {kreg[k].x, kreg[k].y, kreg[k].z, kreg[k].w};
      #pragma unroll
      for (int c = 0; c < 4; ++c) {
        uint32_t key = kv[c];
        if (key >= thr) {
          uint32_t p = atomicAdd(&sh_cnt, 1u);
          if (p < CAP) ent[p] = ((uint64_t)key << 32) | (uint32_t)(~(uint32_t)(4 * i + c));
        }
      }
    }
  }
  __syncthreads();

  // phase 4: register bitonic, 2048 descending, 2 elems/thread
  uint64_t v0 = ent[tid], v1 = ent[tid + 1024];
  for (unsigned kk = 2; kk <= CAP; kk <<= 1) {
    for (unsigned j = kk >> 1; j > 0; j >>= 1) {
      if (j == 1024) {
        uint64_t mx = v0 > v1 ? v0 : v1;
        uint64_t mn = v0 > v1 ? v1 : v0;
        v0 = mx; v1 = mn;  // desc=true for kk=2048
      } else if (j >= 64) {
        __syncthreads();
        ent[tid] = v0; ent[tid + 1024] = v1;
        __syncthreads();
        uint64_t p0 = ent[tid ^ j], p1 = ent[(tid ^ j) + 1024];
        bool low = ((tid & j) == 0);
        bool d0 = ((tid & kk) == 0);
        bool d1 = (((tid + 1024) & kk) == 0);
        v0 = (low != d0) ? (v0 < p0 ? v0 : p0) : (v0 > p0 ? v0 : p0);
        v1 = (low != d1) ? (v1 < p1 ? v1 : p1) : (v1 > p1 ? v1 : p1);
      } else {
        uint64_t p0 = shfl_xor_u64(v0, (int)j);
        uint64_t p1 = shfl_xor_u64(v1, (int)j);
        bool low = ((tid & j) == 0);
        bool d0 = ((tid & kk) == 0);
        bool d1 = (((tid + 1024) & kk) == 0);
        v0 = (low != d0) ? (v0 < p0 ? v0 : p0) : (v0 > p0 ? v0 : p0);
        v1 = (low != d1) ? (v1 < p1 ? v1 : p1) : (v1 > p1 ? v1 : p1);
      }
    }
  }
  uint32_t key = (uint32_t)(v0 >> 32);
  uint32_t n = ~(uint32_t)(v0 & 0xFFFFFFFFu);
  if (n >= NN) n = 0;  // zero-pad path (fewer than 1024 above threshold)
  sel[(size_t)b * TOPK + tid] = (int)n;

  // validity ballot (rank order == tid order; word w covers ranks 32w..32w+31)
  bool valid = key >= KEY_BASE;
  uint64_t bal = __ballot(valid);
  if (lane == 0) {
    vb[(size_t)b * 32 + 2 * wid] = (uint32_t)bal;
    vb[(size_t)b * 32 + 2 * wid + 1] = (uint32_t)(bal >> 32);
  }

  // boxes + areas: the ONE scattered pred gather per image (identical float
  // ops to the original mask conversion, so downstream bits are unchanged)
  {
    const float4* row = (const float4*)(pred + ((size_t)b * NN + n) * NF);
    float4 r0 = row[0];
    float hw = __fmul_rn(r0.z, 0.5f), hh = __fmul_rn(r0.w, 0.5f);
    float x1 = __fsub_rn(r0.x, hw), y1 = __fsub_rn(r0.y, hh);
    float x2 = __fadd_rn(r0.x, hw), y2 = __fadd_rn(r0.y, hh);
    boxv[(size_t)b * TOPK + tid] = make_float4(x1, y1, x2, y2);
    arv[(size_t)b * TOPK + tid] = __fmul_rn(__fsub_rn(x2, x1), __fsub_rn(y2, y1));
  }
}

// R10: fused mask + JACOBI-FIXPOINT scan + output.
// R6-R9 established: the ~50us tail is invariant to scan implementation,
// sync protocol, and cache policy — the one untouched common element is the
// 32x32 ~1000-step SERIAL dependence chain on a single half-wave (single-wave
// dependent-issue latency makes it ~30-40us, not the ~8us an issue-count
// model suggests). R10 ELIMINATES the chain: greedy NMS on a strictly
// upper-triangular suppression matrix is the UNIQUE fixpoint of
//    K = valid & ~S^T K        (uniqueness: induction on smallest index)
// and Jacobi iteration K <- valid & ~S^T K converges to exactly that
// fixpoint (alternating monotone bounds; stability front advances >=1 index
// per sweep -> exact, terminates in <= depth+2 sweeps; ~3-5 for this data).
// Each sweep is a fully parallel bitmask mat-vec over all 1024 threads:
// thread (l=tid&31, chunk=tid>>5) ORs the kept rows chunk*32..+31 of mask
// word l from LDS (pitch-257 uint4 rows -> 4-way-max bank spread), then a
// 32-wide OR-reduce + convergence ballot. No readlane, no serial chain.
__global__ __launch_bounds__(1024, 4) void k_maskscan(const float* __restrict__ pred,
                                                      const int* __restrict__ sel,
                                                      const float4* __restrict__ boxv,
                                                      const float* __restrict__ arv,
                                                      const uint32_t* __restrict__ vb,
                                                      uint32_t* __restrict__ mask,
                                                      uint32_t* __restrict__ cnt,
                                                      float* __restrict__ det,
                                                      float* __restrict__ keep_out) {
  int b = blockIdx.x;
  int sblk = blockIdx.y;
  int tid = threadIdx.x;
  int rg = tid & 31;
  int cc = tid >> 5;
  __shared__ uint4 sm4[32 * PITCH];      // 131.6 KB staged mask, pitch-257
  __shared__ uint32_t part[1024];
  __shared__ uint32_t Kvec[32];
  __shared__ uint32_t vbs[32];
  __shared__ uint32_t sflag;
  // phase-A overlay: box arrays live in the first 20 KB of sm4
  float* bx1 = (float*)sm4;
  float* by1 = bx1 + TOPK;
  float* bx2 = by1 + TOPK;
  float* by2 = bx2 + TOPK;
  float* bar = by2 + TOPK;

  // ---- phase A: mask slab (identical arithmetic to R6-R9) ----
  {
    float4 bb = boxv[(size_t)b * TOPK + tid];
    bx1[tid] = bb.x; by1[tid] = bb.y; bx2[tid] = bb.z; by2[tid] = bb.w;
    bar[tid] = arv[(size_t)b * TOPK + tid];
  }
  __syncthreads();
  int i0 = sblk * 128 + rg * 4;   // rows i0..i0+3, all in word iw
  int iw = i0 >> 5;
  uint32_t wreg[4] = {0u, 0u, 0u, 0u};
  if (cc >= iw) {
    float rx1[4], ry1[4], rx2[4], ry2[4], rar[4];
    #pragma unroll
    for (int k = 0; k < 4; ++k) {
      rx1[k] = bx1[i0 + k]; ry1[k] = by1[i0 + k];
      rx2[k] = bx2[i0 + k]; ry2[k] = by2[i0 + k]; rar[k] = bar[i0 + k];
    }
    for (int jj = 0; jj < 32; ++jj) {
      int j = cc * 32 + jj;
      float cx1 = bx1[j], cy1 = by1[j], cx2 = bx2[j], cy2 = by2[j], car = bar[j];
      #pragma unroll
      for (int k = 0; k < 4; ++k) {
        float lx = fmaxf(rx1[k], cx1);
        float ly = fmaxf(ry1[k], cy1);
        float rx = fminf(rx2[k], cx2);
        float ry = fminf(ry2[k], cy2);
        float wd = fmaxf(__fsub_rn(rx, lx), 0.0f);
        float ht = fmaxf(__fsub_rn(ry, ly), 0.0f);
        float inter = __fmul_rn(wd, ht);
        float den = __fadd_rn(__fsub_rn(__fadd_rn(rar[k], car), inter), 1e-7f);
        float iou = __fdiv_rn(inter, den);
        wreg[k] |= (iou > IOU_T ? 1u : 0u) << jj;
      }
    }
    if (cc == iw) {
      #pragma unroll
      for (int k = 0; k < 4; ++k)
        wreg[k] &= ~((2u << ((i0 + k) & 31)) - 1u);  // keep only j > i (strict)
    }
  }
  uint4 out = make_uint4(wreg[0], wreg[1], wreg[2], wreg[3]);
  *(uint4*)&mask[((size_t)b * 32 + cc) * TOPK + i0] = out;

  // publish this slab: barrier drains every thread's vmcnt, then ONE
  // release-add bumps the counter (R6 protocol — relaxed polls on the other
  // side; this combination measured 57us faster than acquire-polling).
  __syncthreads();
  if (tid == 0)
    __hip_atomic_fetch_add(&cnt[b], 1u, __ATOMIC_RELEASE, __HIP_MEMORY_SCOPE_AGENT);
  if (sblk != 0) return;

  // ---- phase B (sblk==0 only) ----
  // early-issue the output gather (hides under spin + stage + sweeps)
  int n = sel[(size_t)b * TOPK + tid];
  const float4* rowv = (const float4*)(pred + ((size_t)b * NN + n) * NF);
  float4 r0 = rowv[0], r1 = rowv[1], r2 = rowv[2], r3 = rowv[3];

  if (tid == 0) {
    // RELAXED polls (no cache maintenance); single acquire edge after exit.
    while (__hip_atomic_load(&cnt[b], __ATOMIC_RELAXED, __HIP_MEMORY_SCOPE_AGENT) < 8u)
      __builtin_amdgcn_s_sleep(16);
    (void)__hip_atomic_load(&cnt[b], __ATOMIC_ACQUIRE, __HIP_MEMORY_SCOPE_AGENT);
  }
  __syncthreads();

  // bulk stage: 1024 threads x 8 uint4 = 128 KiB, coalesced reads, pitch-257
  // LDS rows (row r starts at uint4 index r*257 -> (l + col)%8 bank spread).
  const uint4* gm4 = (const uint4*)(mask + (size_t)b * (32 * TOPK));
  #pragma unroll
  for (int q = 0; q < 8; ++q) {
    int idx4 = tid + q * 1024;          // uint4 index 0..8191
    int row = idx4 >> 8;                // 256 uint4 per mask word-row
    int col4 = idx4 & 255;
    sm4[row * PITCH + col4] = gm4[idx4];
  }
  if (tid < 32) { uint32_t v = vb[(size_t)b * 32 + tid]; vbs[tid] = v; Kvec[tid] = v; }
  __syncthreads();

  // Jacobi sweeps: K <- vb & ~S^T K until fixpoint (== exact greedy keep).
  {
    int l = tid & 31;                    // mask word this thread accumulates
    int chunk = tid >> 5;                // row block chunk*32..chunk*32+31
    const int rbase = l * PITCH + chunk * 8;
    uint32_t go = 1u;
    for (int sweep = 0; sweep < 1030 && go; ++sweep) {
      uint32_t kc = Kvec[chunk];         // kept bits for this row block
      uint32_t acc = 0;
      #pragma unroll
      for (int q = 0; q < 8; ++q) {
        uint4 v = sm4[rbase + q];
        acc |= (0u - ((kc >> (q * 4 + 0)) & 1u)) & v.x;
        acc |= (0u - ((kc >> (q * 4 + 1)) & 1u)) & v.y;
        acc |= (0u - ((kc >> (q * 4 + 2)) & 1u)) & v.z;
        acc |= (0u - ((kc >> (q * 4 + 3)) & 1u)) & v.w;
      }
      part[tid] = acc;
      __syncthreads();
      if (tid < 32) {
        uint32_t red = 0;
        #pragma unroll
        for (int c = 0; c < 32; ++c) red |= part[c * 32 + tid];
        uint32_t nk = vbs[tid] & ~red;
        uint64_t chg = __ballot(nk != Kvec[tid]);
        Kvec[tid] = nk;
        if (tid == 0) sflag = (chg != 0ull) ? 1u : 0u;
      }
      __syncthreads();
      go = sflag;
    }
  }

  // output phase: row already in registers (gathered before the spin)
  bool kept = (Kvec[tid >> 5] >> (tid & 31)) & 1u;
  float m = kept ? 1.0f : 0.0f;
  float score = __fmul_rn(r3.w, r1.x);   // == cls*obj, identical to reference path
  float hw = __fmul_rn(r0.z, 0.5f), hh = __fmul_rn(r0.w, 0.5f);
  float4 o0 = make_float4(__fsub_rn(r0.x, hw) * m, __fsub_rn(r0.y, hh) * m,
                          __fadd_rn(r0.x, hw) * m, __fadd_rn(r0.y, hh) * m);
  float4 o1 = make_float4(score * m, r1.y * m, r1.z * m, r1.w * m);
  float4 o2 = make_float4(r2.x * m, r2.y * m, r2.z * m, r2.w * m);
  float4 o3 = make_float4(r3.x * m, r3.y * m, r3.z * m, 0.0f);
  float4* dst = (float4*)(det + ((size_t)b * TOPK + tid) * NF);
  dst[0] = o0; dst[1] = o1; dst[2] = o2; dst[3] = o3;
  keep_out[(size_t)b * TOPK + tid] = m;
}

extern "C" void kernel_launch(void* const* d_in, const int* in_sizes, int n_in,
                              void* d_out, int out_size, void* d_ws, size_t ws_size,
                              hipStream_t stream) {
  const float* pred = (const float*)d_in[0];
  float* det = (float*)d_out;
  float* keep = det + (size_t)NB * TOPK * NF;

  uint8_t* ws = (uint8_t*)d_ws;
  size_t off = 0;
  uint32_t* keys = (uint32_t*)(ws + off); off += (size_t)NB * NN * 4;
  int* sel = (int*)(ws + off);            off += (size_t)NB * TOPK * 4;
  uint32_t* mask = (uint32_t*)(ws + off); off += (size_t)NB * 32 * TOPK * 4;
  float4* boxv = (float4*)(ws + off);     off += (size_t)NB * TOPK * 16;
  float* arv = (float*)(ws + off);        off += (size_t)NB * TOPK * 4;
  uint32_t* vb = (uint32_t*)(ws + off);   off += (size_t)NB * 32 * 4;
  uint32_t* cnt = (uint32_t*)(ws + off);  off += (size_t)NB * 4;

  k_keys<<<(NB * NN + 255) / 256, 256, 0, stream>>>(pred, keys, cnt);
  k_select<<<NB, 1024, 0, stream>>>(pred, keys, sel, boxv, arv, vb);
  dim3 gm(NB, 8);
  k_maskscan<<<gm, 1024, 0, stream>>>(pred, sel, boxv, arv, vb, mask, cnt, det, keep);
}